// Round 1
// baseline (1256.321 us; speedup 1.0000x reference)
//
#include <hip/hip_runtime.h>
#include <stdint.h>
#include <stddef.h>

// Problem constants: B=2, T=8192, D=2048, W=128
#define Bn 2
#define Tn 8192
#define Dn 2048

typedef unsigned short u16;
typedef unsigned int u32;
typedef __attribute__((ext_vector_type(8))) short short8;      // 8 bf16 = 4 VGPR (MFMA A/B frag)
typedef __attribute__((ext_vector_type(8))) unsigned short u16x8;
typedef __attribute__((ext_vector_type(4))) float f32x4;       // MFMA C/D frag

__device__ __forceinline__ u16 f2bf(float f) {
  u32 x = __builtin_bit_cast(u32, f);
  x += 0x7fffu + ((x >> 16) & 1u);   // round-nearest-even (inputs are finite)
  return (u16)(x >> 16);
}

// async global->LDS, 16B per lane. LDS dest must be wave-uniform; HW writes
// ldsbase + lane*16. Global ptr is per-lane.
__device__ __forceinline__ void gload16(void* lds, const void* g) {
  __builtin_amdgcn_global_load_lds(
      (const __attribute__((address_space(1))) u32*)g,
      (__attribute__((address_space(3))) u32*)lds, 16, 0, 0);
}

// ---------------- cast fp32 -> bf16 ----------------
__global__ void cast_kernel(const float* __restrict__ in, u16* __restrict__ out, int n) {
  int stride = gridDim.x * blockDim.x;
  for (int i = blockIdx.x * blockDim.x + threadIdx.x; i < (n >> 2); i += stride) {
    float4 v = reinterpret_cast<const float4*>(in)[i];
    ushort4 o;
    o.x = f2bf(v.x); o.y = f2bf(v.y); o.z = f2bf(v.z); o.w = f2bf(v.w);
    reinterpret_cast<ushort4*>(out)[i] = o;
  }
}

// ---------------- 128x128 tile NT GEMM (m97 structure) ----------------
// C[m][n] = sum_k A[m][k] * Bw[n][k]   (both row-major along K)
// MODE 0: QKV epilogue -> bf16 q (scaled 1/128), k, v buffers (each M x 2048)
// MODE 1: fp32 out, N = 2048
template <int MODE>
__global__ __launch_bounds__(256) void gemm_nt(
    const u16* __restrict__ A, const u16* __restrict__ Bw,
    u16* __restrict__ Oq, u16* __restrict__ Ok, u16* __restrict__ Ov,
    float* __restrict__ Of, int K) {
  __shared__ u16 As[128 * 32];   // 8 KB
  __shared__ u16 Bs[128 * 32];   // 8 KB
  const int tid = threadIdx.x;
  const int lane = tid & 63;
  const int wid = tid >> 6;              // 0..3
  const int wm = wid >> 1, wn = wid & 1; // 2x2 wave grid, 64x64 each
  const int m0 = blockIdx.x * 128, n0 = blockIdx.y * 128;

  const int srow = lane >> 2;          // row within 16-row chunk (64B rows)
  const int scol = (lane & 3) * 8;     // k-elem offset
  const int fr = lane & 15;            // frag row/col
  const int kk = (lane >> 4) * 8;      // frag k offset

  f32x4 acc[4][4] = {};
  const size_t aBase = (size_t)m0 * K;
  const size_t bBase = (size_t)n0 * K;

  for (int k0 = 0; k0 < K; k0 += 32) {
#pragma unroll
    for (int i = 0; i < 2; ++i) {
      int chunk = wid * 2 + i;           // 8 chunks of 16 rows each
      int row = chunk * 16 + srow;
      gload16(As + chunk * 512, A + aBase + (size_t)row * K + k0 + scol);
      gload16(Bs + chunk * 512, Bw + bBase + (size_t)row * K + k0 + scol);
    }
    __syncthreads();
    short8 av[4], bv[4];
#pragma unroll
    for (int f = 0; f < 4; ++f) {
      av[f] = *reinterpret_cast<const short8*>(&As[(wm * 64 + f * 16 + fr) * 32 + kk]);
      bv[f] = *reinterpret_cast<const short8*>(&Bs[(wn * 64 + f * 16 + fr) * 32 + kk]);
    }
#pragma unroll
    for (int fm = 0; fm < 4; ++fm)
#pragma unroll
      for (int fn = 0; fn < 4; ++fn)
        acc[fm][fn] = __builtin_amdgcn_mfma_f32_16x16x32_bf16(av[fm], bv[fn], acc[fm][fn], 0, 0, 0);
    __syncthreads();
  }

  // epilogue: C row = (lane>>4)*4 + r, col = lane&15 (verified layout)
  const int ci = (lane >> 4) * 4;
  if (MODE == 0) {
    u16* Cb;
    float scale = 1.0f;
    if (n0 < Dn) { Cb = Oq; scale = 1.0f / 128.0f; }
    else if (n0 < 2 * Dn) Cb = Ok;
    else Cb = Ov;
    const int nl0 = n0 & (Dn - 1);
#pragma unroll
    for (int fm = 0; fm < 4; ++fm)
#pragma unroll
      for (int fn = 0; fn < 4; ++fn) {
        int row = m0 + wm * 64 + fm * 16 + ci;
        int col = nl0 + wn * 64 + fn * 16 + fr;
#pragma unroll
        for (int r = 0; r < 4; ++r)
          Cb[(size_t)(row + r) * Dn + col] = f2bf(acc[fm][fn][r] * scale);
      }
  } else {
#pragma unroll
    for (int fm = 0; fm < 4; ++fm)
#pragma unroll
      for (int fn = 0; fn < 4; ++fn) {
        int row = m0 + wm * 64 + fm * 16 + ci;
        int col = n0 + wn * 64 + fn * 16 + fr;
#pragma unroll
        for (int r = 0; r < 4; ++r)
          Of[(size_t)(row + r) * Dn + col] = acc[fm][fn][r];
      }
  }
}

// ---------------- v (B,T,D) -> vT (B,D,T) transpose ----------------
__global__ __launch_bounds__(256) void transpose_kernel(
    const u16* __restrict__ vin, u16* __restrict__ vout) {
  __shared__ u16 tile[64][72];   // +8 pad
  const int b = blockIdx.z;
  const int t0 = blockIdx.x * 64, d0 = blockIdx.y * 64;
  const int tid = threadIdx.x;
#pragma unroll
  for (int i = 0; i < 2; ++i) {
    int chunk = tid + i * 256;          // 512 chunks of 8 elems
    int row = chunk >> 3;               // t
    int col = (chunk & 7) * 8;          // d
    u16x8 v = *reinterpret_cast<const u16x8*>(
        vin + ((size_t)b * Tn + t0 + row) * Dn + d0 + col);
#pragma unroll
    for (int j = 0; j < 8; ++j) tile[row][col + j] = v[j];
  }
  __syncthreads();
#pragma unroll
  for (int i = 0; i < 2; ++i) {
    int chunk = tid + i * 256;
    int drow = chunk >> 3;              // d
    int tcol = (chunk & 7) * 8;         // t
    u16x8 v;
#pragma unroll
    for (int j = 0; j < 8; ++j) v[j] = tile[tcol + j][drow];
    *reinterpret_cast<u16x8*>(vout + ((size_t)b * Dn + d0 + drow) * Tn + t0 + tcol) = v;
  }
}

// ---------------- block attention ----------------
// 1 WG per (b, blk). 8 waves / 512 threads.
// phase1: sim (128x256) = Qblk @ K2^T, wave grid 2x4, acc in regs
// phase2: mask + relu^2 -> P bf16 in LDS [128][264]
// phase3: out (128x2048) = P @ V2, loop 32 chunks of 64 d-cols, Vt staged in LDS
__global__ __launch_bounds__(512) void attn_kernel(
    const u16* __restrict__ q, const u16* __restrict__ k,
    const u16* __restrict__ vT, u16* __restrict__ ao) {
  __shared__ u16 sStage[16384];        // ph1: Qs[0..4096)=128x32, Ks[4096..12288)=256x32 ; ph3: Vts 64x256
  __shared__ u16 sP[128 * 264];        // P, padded rows
  u16* Qs = sStage;
  u16* Ks = sStage + 4096;
  u16* Vts = sStage;

  const int bid = blockIdx.x;
  const int b = bid >> 6, blk = bid & 63;
  const int tid = threadIdx.x, lane = tid & 63, wid = tid >> 6;  // wid 0..7
  const int tprev = blk * 128 - 128;

  const u16* qp = q + ((size_t)b * Tn + blk * 128) * Dn;
  const u16* kp = k + (size_t)b * Tn * Dn;
  const u16* vp = vT + (size_t)b * Dn * Tn;

  const int wm = wid >> 2, wn = wid & 3;     // 2x4 wave grid
  const int srow = lane >> 2, scol = (lane & 3) * 8;
  const int fr = lane & 15, kk = (lane >> 4) * 8;

  // ---- phase 1 ----
  f32x4 acc[4][4] = {};
  for (int k0 = 0; k0 < Dn; k0 += 32) {
    {
      int row = wid * 16 + srow;             // Q rows, chunk = wid
      gload16(Qs + wid * 512, qp + (size_t)row * Dn + k0 + scol);
    }
#pragma unroll
    for (int i = 0; i < 2; ++i) {
      int chunk = wid * 2 + i;               // 16 chunks of 16 key-rows
      int j = chunk * 16 + srow;
      int trow = tprev + j;
      if (trow < 0) trow = 0;                // pad rows: values masked later
      gload16(Ks + chunk * 512, kp + (size_t)trow * Dn + k0 + scol);
    }
    __syncthreads();
    short8 av[4], bv[4];
#pragma unroll
    for (int f = 0; f < 4; ++f) {
      av[f] = *reinterpret_cast<const short8*>(&Qs[(wm * 64 + f * 16 + fr) * 32 + kk]);
      bv[f] = *reinterpret_cast<const short8*>(&Ks[(wn * 64 + f * 16 + fr) * 32 + kk]);
    }
#pragma unroll
    for (int fm = 0; fm < 4; ++fm)
#pragma unroll
      for (int fn = 0; fn < 4; ++fn)
        acc[fm][fn] = __builtin_amdgcn_mfma_f32_16x16x32_bf16(av[fm], bv[fn], acc[fm][fn], 0, 0, 0);
    __syncthreads();
  }

  // ---- phase 2: mask + relu^2 -> P ----
  {
    const int ci = (lane >> 4) * 4;
#pragma unroll
    for (int fm = 0; fm < 4; ++fm)
#pragma unroll
      for (int fn = 0; fn < 4; ++fn)
#pragma unroll
        for (int r = 0; r < 4; ++r) {
          int i = wm * 64 + fm * 16 + ci + r;     // query row 0..127
          int j = wn * 64 + fn * 16 + fr;         // key 0..255 (0..127 = prev block)
          float s = acc[fm][fn][r];
          bool keep = (j < 128) ? (blk > 0 && i <= j) : (i >= j - 128);
          float p = (keep && s > 0.0f) ? s * s : 0.0f;
          sP[i * 264 + j] = f2bf(p);
        }
  }
  __syncthreads();

  // ---- phase 3: out = P @ V2, 32 chunks of 64 d-cols ----
  for (int c = 0; c < 32; ++c) {
#pragma unroll
    for (int i = 0; i < 4; ++i) {
      int chunk = wid * 4 + i;                 // 32 chunks of 2 d-rows (512B rows)
      int d = c * 64 + chunk * 2 + (lane >> 5);
      int t = tprev + (lane & 31) * 8;
      if (t < 0) t = 0;                        // pad: P is 0 there
      gload16(Vts + chunk * 512, vp + (size_t)d * Tn + t);
    }
    __syncthreads();
    f32x4 pacc[4] = {};
#pragma unroll
    for (int ks = 0; ks < 8; ++ks) {
      short8 a = *reinterpret_cast<const short8*>(&sP[(wid * 16 + fr) * 264 + ks * 32 + kk]);
#pragma unroll
      for (int fn = 0; fn < 4; ++fn) {
        short8 bv2 = *reinterpret_cast<const short8*>(&Vts[(fn * 16 + fr) * 256 + ks * 32 + kk]);
        pacc[fn] = __builtin_amdgcn_mfma_f32_16x16x32_bf16(a, bv2, pacc[fn], 0, 0, 0);
      }
    }
    const int ci = (lane >> 4) * 4;
    int trow = blk * 128 + wid * 16 + ci;
#pragma unroll
    for (int fn = 0; fn < 4; ++fn) {
      int d = c * 64 + fn * 16 + fr;
#pragma unroll
      for (int r = 0; r < 4; ++r)
        ao[((size_t)b * Tn + trow + r) * Dn + d] = f2bf(pacc[fn][r]);
    }
    __syncthreads();
  }
}

extern "C" void kernel_launch(void* const* d_in, const int* in_sizes, int n_in,
                              void* d_out, int out_size, void* d_ws, size_t ws_size,
                              hipStream_t stream) {
  const float* x = (const float*)d_in[0];
  const float* w_attn = (const float*)d_in[1];
  const float* w_o = (const float*)d_in[2];
  float* out = (float*)d_out;

  // workspace layout (bf16 buffers), total = 302 MB
  char* ws = (char*)d_ws;
  u16* xb  = (u16*)(ws + 0);            // 64 MB  (B*T*D)
  u16* wb  = (u16*)(ws + 67108864);     // 24 MB  (3D*D)
  u16* wob = (u16*)(ws + 92274688);     // 8 MB   (D*D)
  u16* qb  = (u16*)(ws + 100663296);    // 64 MB
  u16* kb  = (u16*)(ws + 167772160);    // 64 MB
  u16* vb  = (u16*)(ws + 234881024);    // 64 MB
  u16* vTb = xb;   // reuse: xb dead after QKV GEMM
  u16* ao  = vb;   // reuse: vb dead after transpose

  cast_kernel<<<2048, 256, 0, stream>>>(x, xb, Bn * Tn * Dn);
  cast_kernel<<<1024, 256, 0, stream>>>(w_attn, wb, 3 * Dn * Dn);
  cast_kernel<<<512, 256, 0, stream>>>(w_o, wob, Dn * Dn);

  // qkv = x @ w_attn^T  (M=16384, N=6144, K=2048)
  gemm_nt<0><<<dim3(128, 48), 256, 0, stream>>>(xb, wb, qb, kb, vb, nullptr, Dn);

  // vT (B,D,T)
  transpose_kernel<<<dim3(128, 32, 2), 256, 0, stream>>>(vb, vTb);

  // block attention
  attn_kernel<<<128, 512, 0, stream>>>(qb, kb, vTb, ao);

  // out = attn_out @ w_o^T  (M=16384, N=2048, K=2048), fp32 out
  gemm_nt<1><<<dim3(128, 16), 256, 0, stream>>>(ao, wob, nullptr, nullptr, nullptr, out, Dn);
}

// Round 2
// 1030.209 us; speedup vs baseline: 1.2195x; 1.2195x over previous
//
#include <hip/hip_runtime.h>
#include <stdint.h>
#include <stddef.h>

// Problem constants: B=2, T=8192, D=2048, W=128
#define Bn 2
#define Tn 8192
#define Dn 2048

typedef unsigned short u16;
typedef unsigned int u32;
typedef __attribute__((ext_vector_type(8))) short short8;      // 8 bf16 = 4 VGPR (MFMA A/B frag)
typedef __attribute__((ext_vector_type(8))) unsigned short u16x8;
typedef __attribute__((ext_vector_type(4))) float f32x4;       // MFMA C/D frag

__device__ __forceinline__ u16 f2bf(float f) {
  u32 x = __builtin_bit_cast(u32, f);
  x += 0x7fffu + ((x >> 16) & 1u);   // round-nearest-even (inputs are finite)
  return (u16)(x >> 16);
}

// async global->LDS, 16B per lane. LDS dest must be wave-uniform; HW writes
// ldsbase + lane*16. Global ptr is per-lane.
__device__ __forceinline__ void gload16(void* lds, const void* g) {
  __builtin_amdgcn_global_load_lds(
      (const __attribute__((address_space(1))) u32*)g,
      (__attribute__((address_space(3))) u32*)lds, 16, 0, 0);
}

#define PH_BAR asm volatile("s_barrier" ::: "memory")
#define WAITV(N) asm volatile("s_waitcnt vmcnt(" #N ")" ::: "memory")

// ---------------- cast fp32 -> bf16 ----------------
__global__ void cast_kernel(const float* __restrict__ in, u16* __restrict__ out, int n) {
  int stride = gridDim.x * blockDim.x;
  for (int i = blockIdx.x * blockDim.x + threadIdx.x; i < (n >> 2); i += stride) {
    float4 v = reinterpret_cast<const float4*>(in)[i];
    ushort4 o;
    o.x = f2bf(v.x); o.y = f2bf(v.y); o.z = f2bf(v.z); o.w = f2bf(v.w);
    reinterpret_cast<ushort4*>(out)[i] = o;
  }
}

// ---------------- 256x256 8-phase NT GEMM (m201 template) ----------------
// C[m][n] = sum_k A[m][k] * Bw[n][k] (both row-major along K, K%64==0)
// 8 waves (2M x 4N), per-wave output 128x64. BK=64. LDS 128 KiB:
//   A: [db][half(128rows)][128x64 bf16]  bytes [0, 65536)
//   B: same, bytes [65536, 131072)
// st_16x32 swizzle: byte ^= ((byte>>9)&1)<<5, applied as inverse-swizzled
// global source (linear global_load_lds dest) + swizzled ds_read offset.
// Schedule per K-tile t (db = t&1):
//  ph1: read A[fm0-3]+B[fn0-1]; stage A0(t+1)->db^1 ; bar; MFMA q(0,0); bar
//  ph2: read B[fn2-3];          stage A1(t+1)->db^1 ; bar; MFMA q(0,1); bar
//  ph3: read A[fm4-7];          stage B0(t+2)->db   ; bar; MFMA q(1,0); bar
//  ph4: (no reads);             stage B1(t+2)->db   ; bar; MFMA q(1,1);
//       vmcnt(4); bar
// Region safety: A-halves of db^1 last read in (t-1).ph3 (barrier-sealed);
// B-halves of db last read in t.ph2 (barrier-sealed before ph3/ph4 stages).
// vmcnt(4): after A1(t+1) (newest half needed by t+1) only B0/B1(t+2) =
// 4 loads are outstanding.
template <int MODE>
__global__ __launch_bounds__(512, 2) void gemm256(
    const u16* __restrict__ Ag, const u16* __restrict__ Bg,
    u16* __restrict__ Oq, u16* __restrict__ Ok, u16* __restrict__ Ov,
    float* __restrict__ Of, int K) {
  __shared__ char sh[131072];
  const int tid = threadIdx.x, lane = tid & 63, wid = tid >> 6;
  const int wm = wid >> 2, wn = wid & 3;           // 2x4 wave grid
  const int fr = lane & 15, kk = (lane >> 4) * 8;
  const int NT = K >> 6;

  // XCD-aware swizzle (nwg % 8 == 0 for both launches; gridDim.x == 64)
  int lin = blockIdx.y * 64 + blockIdx.x;
  int nwg = gridDim.x * gridDim.y;
  int lin2 = (lin & 7) * (nwg >> 3) + (lin >> 3);
  const int m0 = (lin2 & 63) * 256;
  const int n0 = (lin2 >> 6) * 256;

  // swizzled ds_read base: bit9 of logical offset = (fr>>2)&1 (independent of
  // fm/ks/fn immediates), so the XOR folds into a per-thread constant.
  const int rdoff = (fr * 128 + kk * 2) ^ (((fr >> 2) & 1) << 5);
  // staging: linear LDS dest L = chunk*1024 + lane*16; global source reads
  // logical swz(L): bit9 of L = (lane>>5)&1.
  const int lq = (lane * 16) ^ (((lane >> 5) & 1) << 5);
  const int stgrow = wid * 8 + (lq >> 7);          // row within half (call0)
  const int stgcol = (lq & 127) >> 1;              // elem col (multiple of 8)

  auto stageA = [&](int db, int h, int tt) {
    const u16* s = Ag + (size_t)(m0 + h * 128 + stgrow) * K + tt * 64 + stgcol;
    char* d = sh + db * 32768 + h * 16384 + wid * 1024;
    gload16(d, s);
    gload16(d + 8192, s + (size_t)64 * K);
  };
  auto stageB = [&](int db, int h, int tt) {
    const u16* s = Bg + (size_t)(n0 + h * 128 + stgrow) * K + tt * 64 + stgcol;
    char* d = sh + 65536 + db * 32768 + h * 16384 + wid * 1024;
    gload16(d, s);
    gload16(d + 8192, s + (size_t)64 * K);
  };

  short8 a[4][2], b0[2][2], b1[2][2];
  f32x4 acc[8][4] = {};

  // prologue: tile0 all 4 halves + tile1 B-halves; wait tile0 (4 outstanding)
  stageA(0, 0, 0); stageA(0, 1, 0); stageB(0, 0, 0); stageB(0, 1, 0);
  stageB(1, 0, 1); stageB(1, 1, 1);
  WAITV(4);
  PH_BAR;

  for (int t = 0; t < NT; ++t) {
    const int db = t & 1;
    const char* rdA = sh + db * 32768 + wm * 16384 + rdoff;
    const char* rdB = sh + 65536 + db * 32768 + (wn >> 1) * 16384 + (wn & 1) * 8192 + rdoff;

    // ---- phase 1: quadrant (m-lo, n-lo) ----
#pragma unroll
    for (int fm = 0; fm < 4; ++fm)
#pragma unroll
      for (int ks = 0; ks < 2; ++ks)
        a[fm][ks] = *(const short8*)(rdA + fm * 2048 + ks * 64);
#pragma unroll
    for (int fn = 0; fn < 2; ++fn)
#pragma unroll
      for (int ks = 0; ks < 2; ++ks)
        b0[fn][ks] = *(const short8*)(rdB + fn * 2048 + ks * 64);
    if (t + 1 < NT) stageA(db ^ 1, 0, t + 1);
    PH_BAR;
    __builtin_amdgcn_s_setprio(1);
#pragma unroll
    for (int fm = 0; fm < 4; ++fm)
#pragma unroll
      for (int fn = 0; fn < 2; ++fn)
#pragma unroll
        for (int ks = 0; ks < 2; ++ks)
          acc[fm][fn] = __builtin_amdgcn_mfma_f32_16x16x32_bf16(a[fm][ks], b0[fn][ks], acc[fm][fn], 0, 0, 0);
    __builtin_amdgcn_s_setprio(0);
    PH_BAR;

    // ---- phase 2: quadrant (m-lo, n-hi) ----
#pragma unroll
    for (int fn = 0; fn < 2; ++fn)
#pragma unroll
      for (int ks = 0; ks < 2; ++ks)
        b1[fn][ks] = *(const short8*)(rdB + (2 + fn) * 2048 + ks * 64);
    if (t + 1 < NT) stageA(db ^ 1, 1, t + 1);
    PH_BAR;
    __builtin_amdgcn_s_setprio(1);
#pragma unroll
    for (int fm = 0; fm < 4; ++fm)
#pragma unroll
      for (int fn = 0; fn < 2; ++fn)
#pragma unroll
        for (int ks = 0; ks < 2; ++ks)
          acc[fm][2 + fn] = __builtin_amdgcn_mfma_f32_16x16x32_bf16(a[fm][ks], b1[fn][ks], acc[fm][2 + fn], 0, 0, 0);
    __builtin_amdgcn_s_setprio(0);
    PH_BAR;

    // ---- phase 3: quadrant (m-hi, n-lo) ----
#pragma unroll
    for (int fm = 0; fm < 4; ++fm)
#pragma unroll
      for (int ks = 0; ks < 2; ++ks)
        a[fm][ks] = *(const short8*)(rdA + (4 + fm) * 2048 + ks * 64);
    if (t + 2 < NT) stageB(db, 0, t + 2);
    PH_BAR;
    __builtin_amdgcn_s_setprio(1);
#pragma unroll
    for (int fm = 0; fm < 4; ++fm)
#pragma unroll
      for (int fn = 0; fn < 2; ++fn)
#pragma unroll
        for (int ks = 0; ks < 2; ++ks)
          acc[4 + fm][fn] = __builtin_amdgcn_mfma_f32_16x16x32_bf16(a[fm][ks], b0[fn][ks], acc[4 + fm][fn], 0, 0, 0);
    __builtin_amdgcn_s_setprio(0);
    PH_BAR;

    // ---- phase 4: quadrant (m-hi, n-hi) ----
    if (t + 2 < NT) stageB(db, 1, t + 2);
    PH_BAR;
    __builtin_amdgcn_s_setprio(1);
#pragma unroll
    for (int fm = 0; fm < 4; ++fm)
#pragma unroll
      for (int fn = 0; fn < 2; ++fn)
#pragma unroll
        for (int ks = 0; ks < 2; ++ks)
          acc[4 + fm][2 + fn] = __builtin_amdgcn_mfma_f32_16x16x32_bf16(a[fm][ks], b1[fn][ks], acc[4 + fm][2 + fn], 0, 0, 0);
    __builtin_amdgcn_s_setprio(0);
    if (t + 2 < NT) { WAITV(4); }
    else if (t + 1 < NT) { WAITV(0); }
    PH_BAR;
  }

  // epilogue: C row = (lane>>4)*4 + r, col = lane&15 (verified layout)
  const int ci = (lane >> 4) * 4;
  if (MODE == 0) {
    const int seg = n0 >> 11;            // 0=q, 1=k, 2=v (tiles never straddle)
    u16* Cb = (seg == 0) ? Oq : ((seg == 1) ? Ok : Ov);
    const float scale = (seg == 0) ? (1.0f / 128.0f) : 1.0f;
    const int nl0 = n0 & (Dn - 1);
#pragma unroll
    for (int fm = 0; fm < 8; ++fm)
#pragma unroll
      for (int fn = 0; fn < 4; ++fn) {
        int row = m0 + wm * 128 + fm * 16 + ci;
        int col = nl0 + wn * 64 + fn * 16 + fr;
#pragma unroll
        for (int r = 0; r < 4; ++r)
          Cb[(size_t)(row + r) * Dn + col] = f2bf(acc[fm][fn][r] * scale);
      }
  } else {
#pragma unroll
    for (int fm = 0; fm < 8; ++fm)
#pragma unroll
      for (int fn = 0; fn < 4; ++fn) {
        int row = m0 + wm * 128 + fm * 16 + ci;
        int col = n0 + wn * 64 + fn * 16 + fr;
#pragma unroll
        for (int r = 0; r < 4; ++r)
          Of[(size_t)(row + r) * Dn + col] = acc[fm][fn][r];
      }
  }
}

// ---------------- v (B,T,D) -> vT (B,D,T) transpose ----------------
__global__ __launch_bounds__(256) void transpose_kernel(
    const u16* __restrict__ vin, u16* __restrict__ vout) {
  __shared__ u16 tile[64][72];   // +8 pad
  const int b = blockIdx.z;
  const int t0 = blockIdx.x * 64, d0 = blockIdx.y * 64;
  const int tid = threadIdx.x;
#pragma unroll
  for (int i = 0; i < 2; ++i) {
    int chunk = tid + i * 256;          // 512 chunks of 8 elems
    int row = chunk >> 3;               // t
    int col = (chunk & 7) * 8;          // d
    u16x8 v = *reinterpret_cast<const u16x8*>(
        vin + ((size_t)b * Tn + t0 + row) * Dn + d0 + col);
#pragma unroll
    for (int j = 0; j < 8; ++j) tile[row][col + j] = v[j];
  }
  __syncthreads();
#pragma unroll
  for (int i = 0; i < 2; ++i) {
    int chunk = tid + i * 256;
    int drow = chunk >> 3;              // d
    int tcol = (chunk & 7) * 8;         // t
    u16x8 v;
#pragma unroll
    for (int j = 0; j < 8; ++j) v[j] = tile[tcol + j][drow];
    *reinterpret_cast<u16x8*>(vout + ((size_t)b * Dn + d0 + drow) * Tn + t0 + tcol) = v;
  }
}

// ---------------- block attention ----------------
// 1 WG per (b, blk). 8 waves / 512 threads.
__global__ __launch_bounds__(512) void attn_kernel(
    const u16* __restrict__ q, const u16* __restrict__ k,
    const u16* __restrict__ vT, u16* __restrict__ ao) {
  __shared__ u16 sStage[16384];
  __shared__ u16 sP[128 * 264];
  u16* Qs = sStage;
  u16* Ks = sStage + 4096;
  u16* Vts = sStage;

  const int bid = blockIdx.x;
  const int b = bid >> 6, blk = bid & 63;
  const int tid = threadIdx.x, lane = tid & 63, wid = tid >> 6;
  const int tprev = blk * 128 - 128;

  const u16* qp = q + ((size_t)b * Tn + blk * 128) * Dn;
  const u16* kp = k + (size_t)b * Tn * Dn;
  const u16* vp = vT + (size_t)b * Dn * Tn;

  const int wm = wid >> 2, wn = wid & 3;
  const int srow = lane >> 2, scol = (lane & 3) * 8;
  const int fr = lane & 15, kk = (lane >> 4) * 8;

  // ---- phase 1: sim = Q @ K2^T ----
  f32x4 acc[4][4] = {};
  for (int k0 = 0; k0 < Dn; k0 += 32) {
    {
      int row = wid * 16 + srow;
      gload16(Qs + wid * 512, qp + (size_t)row * Dn + k0 + scol);
    }
#pragma unroll
    for (int i = 0; i < 2; ++i) {
      int chunk = wid * 2 + i;
      int j = chunk * 16 + srow;
      int trow = tprev + j;
      if (trow < 0) trow = 0;
      gload16(Ks + chunk * 512, kp + (size_t)trow * Dn + k0 + scol);
    }
    __syncthreads();
    short8 av[4], bv[4];
#pragma unroll
    for (int f = 0; f < 4; ++f) {
      av[f] = *reinterpret_cast<const short8*>(&Qs[(wm * 64 + f * 16 + fr) * 32 + kk]);
      bv[f] = *reinterpret_cast<const short8*>(&Ks[(wn * 64 + f * 16 + fr) * 32 + kk]);
    }
#pragma unroll
    for (int fm = 0; fm < 4; ++fm)
#pragma unroll
      for (int fn = 0; fn < 4; ++fn)
        acc[fm][fn] = __builtin_amdgcn_mfma_f32_16x16x32_bf16(av[fm], bv[fn], acc[fm][fn], 0, 0, 0);
    __syncthreads();
  }

  // ---- phase 2: mask + relu^2 -> P ----
  {
    const int ci = (lane >> 4) * 4;
#pragma unroll
    for (int fm = 0; fm < 4; ++fm)
#pragma unroll
      for (int fn = 0; fn < 4; ++fn)
#pragma unroll
        for (int r = 0; r < 4; ++r) {
          int i = wm * 64 + fm * 16 + ci + r;
          int j = wn * 64 + fn * 16 + fr;
          float s = acc[fm][fn][r];
          bool keep = (j < 128) ? (blk > 0 && i <= j) : (i >= j - 128);
          float p = (keep && s > 0.0f) ? s * s : 0.0f;
          sP[i * 264 + j] = f2bf(p);
        }
  }
  __syncthreads();

  // ---- phase 3: out = P @ V2 ----
  for (int c = 0; c < 32; ++c) {
#pragma unroll
    for (int i = 0; i < 4; ++i) {
      int chunk = wid * 4 + i;
      int d = c * 64 + chunk * 2 + (lane >> 5);
      int t = tprev + (lane & 31) * 8;
      if (t < 0) t = 0;
      gload16(Vts + chunk * 512, vp + (size_t)d * Tn + t);
    }
    __syncthreads();
    f32x4 pacc[4] = {};
#pragma unroll
    for (int ks = 0; ks < 8; ++ks) {
      short8 a = *reinterpret_cast<const short8*>(&sP[(wid * 16 + fr) * 264 + ks * 32 + kk]);
#pragma unroll
      for (int fn = 0; fn < 4; ++fn) {
        short8 bv2 = *reinterpret_cast<const short8*>(&Vts[(fn * 16 + fr) * 256 + ks * 32 + kk]);
        pacc[fn] = __builtin_amdgcn_mfma_f32_16x16x32_bf16(a, bv2, pacc[fn], 0, 0, 0);
      }
    }
    const int ci = (lane >> 4) * 4;
    int trow = blk * 128 + wid * 16 + ci;
#pragma unroll
    for (int fn = 0; fn < 4; ++fn) {
      int d = c * 64 + fn * 16 + fr;
#pragma unroll
      for (int r = 0; r < 4; ++r)
        ao[((size_t)b * Tn + trow + r) * Dn + d] = f2bf(pacc[fn][r]);
    }
    __syncthreads();
  }
}

extern "C" void kernel_launch(void* const* d_in, const int* in_sizes, int n_in,
                              void* d_out, int out_size, void* d_ws, size_t ws_size,
                              hipStream_t stream) {
  const float* x = (const float*)d_in[0];
  const float* w_attn = (const float*)d_in[1];
  const float* w_o = (const float*)d_in[2];
  float* out = (float*)d_out;

  char* ws = (char*)d_ws;
  u16* xb  = (u16*)(ws + 0);            // 64 MB  (B*T*D)
  u16* wb  = (u16*)(ws + 67108864);     // 24 MB  (3D*D)
  u16* wob = (u16*)(ws + 92274688);     // 8 MB   (D*D)
  u16* qb  = (u16*)(ws + 100663296);    // 64 MB
  u16* kb  = (u16*)(ws + 167772160);    // 64 MB
  u16* vb  = (u16*)(ws + 234881024);    // 64 MB
  u16* vTb = xb;   // reuse: xb dead after QKV GEMM
  u16* ao  = vb;   // reuse: vb dead after transpose

  cast_kernel<<<2048, 256, 0, stream>>>(x, xb, Bn * Tn * Dn);
  cast_kernel<<<1024, 256, 0, stream>>>(w_attn, wb, 3 * Dn * Dn);
  cast_kernel<<<512, 256, 0, stream>>>(w_o, wob, Dn * Dn);

  // qkv = x @ w_attn^T  (M=16384, N=6144, K=2048)
  gemm256<0><<<dim3(64, 24), 512, 0, stream>>>(xb, wb, qb, kb, vb, nullptr, Dn);

  // vT (B,D,T)
  transpose_kernel<<<dim3(128, 32, 2), 256, 0, stream>>>(vb, vTb);

  // block attention
  attn_kernel<<<128, 512, 0, stream>>>(qb, kb, vTb, ao);

  // out = attn_out @ w_o^T  (M=16384, N=2048, K=2048), fp32 out
  gemm256<1><<<dim3(64, 8), 512, 0, stream>>>(ao, wob, nullptr, nullptr, nullptr, out, Dn);
}

// Round 3
// 911.118 us; speedup vs baseline: 1.3789x; 1.1307x over previous
//
#include <hip/hip_runtime.h>
#include <stdint.h>
#include <stddef.h>

// Problem constants: B=2, T=8192, D=2048, W=128
#define Bn 2
#define Tn 8192
#define Dn 2048

typedef unsigned short u16;
typedef unsigned int u32;
typedef __attribute__((ext_vector_type(8))) short short8;      // 8 bf16 = 4 VGPR (MFMA A/B frag)
typedef __attribute__((ext_vector_type(8))) unsigned short u16x8;
typedef __attribute__((ext_vector_type(4))) float f32x4;       // MFMA C/D frag

__device__ __forceinline__ u16 f2bf(float f) {
  u32 x = __builtin_bit_cast(u32, f);
  x += 0x7fffu + ((x >> 16) & 1u);   // round-nearest-even (inputs are finite)
  return (u16)(x >> 16);
}

// async global->LDS, 16B per lane. LDS dest must be wave-uniform; HW writes
// ldsbase + lane*16. Global ptr is per-lane.
__device__ __forceinline__ void gload16(void* lds, const void* g) {
  __builtin_amdgcn_global_load_lds(
      (const __attribute__((address_space(1))) u32*)g,
      (__attribute__((address_space(3))) u32*)lds, 16, 0, 0);
}

#define PH_BAR asm volatile("s_barrier" ::: "memory")
#define WAITV(N) asm volatile("s_waitcnt vmcnt(" #N ")" ::: "memory")

// ---------------- cast fp32 -> bf16 ----------------
__global__ void cast_kernel(const float* __restrict__ in, u16* __restrict__ out, int n) {
  int stride = gridDim.x * blockDim.x;
  for (int i = blockIdx.x * blockDim.x + threadIdx.x; i < (n >> 2); i += stride) {
    float4 v = reinterpret_cast<const float4*>(in)[i];
    ushort4 o;
    o.x = f2bf(v.x); o.y = f2bf(v.y); o.z = f2bf(v.z); o.w = f2bf(v.w);
    reinterpret_cast<ushort4*>(out)[i] = o;
  }
}

// ---------------- 256x256 8-phase NT GEMM ----------------
// C[m][n] = sum_k A[m][k] * Bw[n][k] (row-major along K, K%64==0)
// 8 waves (2M x 4N), per-wave output 128x64. BK=64. LDS 128 KiB.
// Swizzle (G4/m214, verified): physical_byte = logical_byte ^ ((row&7)<<4)
// within each 128B-row half-tile. Stage side: linear global_load_lds dest +
// inverse-swizzled global source col. Read side: bits4-5 of the XOR fold into
// a per-thread base; bit6 selects between two bases (koff0/koff1) by ks parity.
template <int MODE>
__global__ __launch_bounds__(512, 2) void gemm256(
    const u16* __restrict__ Ag, const u16* __restrict__ Bg,
    u16* __restrict__ Oq, u16* __restrict__ Ok, u16* __restrict__ Ov,
    float* __restrict__ Of, int K) {
  __shared__ char sh[131072];
  const int tid = threadIdx.x, lane = tid & 63, wid = tid >> 6;
  const int wm = wid >> 2, wn = wid & 3;           // 2x4 wave grid
  const int fr = lane & 15;
  const int NT = K >> 6;

  // XCD-aware swizzle (nwg % 8 == 0 for both launches; gridDim.x == 64)
  int lin = blockIdx.y * 64 + blockIdx.x;
  int nwg = gridDim.x * gridDim.y;
  int lin2 = (lin & 7) * (nwg >> 3) + (lin >> 3);
  const int m0 = (lin2 & 63) * 256;
  const int n0 = (lin2 >> 6) * 256;

  // read-side swizzle constants
  const int frb2 = (fr >> 2) & 1;
  const int kkb = (lane >> 4) * 16;                     // frag k byte offset
  const int rdoff = fr * 128 + (kkb ^ ((fr & 3) << 4)); // bits4-5 of mask folded
  const int koff0 = frb2 * 64;                          // bit6 of mask, ks=0
  const int koff1 = 64 - koff0;                         // ks=1

  // stage-side: physical chunk byte = lane*16 -> row lane>>3, block lane&7;
  // logical col block = (lane&7) ^ (lane>>3)
  const int srow8 = lane >> 3;
  const int scol8 = ((lane & 7) ^ srow8) * 8;

  auto stageA = [&](int db, int h, int tt) {
    const u16* s = Ag + (size_t)(m0 + h * 128 + wid * 8 + srow8) * K + tt * 64 + scol8;
    char* d = sh + db * 32768 + h * 16384 + wid * 1024;
    gload16(d, s);
    gload16(d + 8192, s + (size_t)64 * K);
  };
  auto stageB = [&](int db, int h, int tt) {
    const u16* s = Bg + (size_t)(n0 + h * 128 + wid * 8 + srow8) * K + tt * 64 + scol8;
    char* d = sh + 65536 + db * 32768 + h * 16384 + wid * 1024;
    gload16(d, s);
    gload16(d + 8192, s + (size_t)64 * K);
  };

  short8 a[4][2], b0[2][2], b1[2][2];
  f32x4 acc[8][4] = {};

  // prologue: tile0 all 4 halves + tile1 B-halves; wait tile0 (4 outstanding)
  stageA(0, 0, 0); stageA(0, 1, 0); stageB(0, 0, 0); stageB(0, 1, 0);
  stageB(1, 0, 1); stageB(1, 1, 1);
  WAITV(4);
  PH_BAR;

  for (int t = 0; t < NT; ++t) {
    const int db = t & 1;
    const char* rdA = sh + db * 32768 + wm * 16384 + rdoff;
    const char* rdB = sh + 65536 + db * 32768 + (wn >> 1) * 16384 + (wn & 1) * 8192 + rdoff;

    // ---- phase 1: quadrant (m-lo, n-lo) ----
#pragma unroll
    for (int fm = 0; fm < 4; ++fm)
#pragma unroll
      for (int ks = 0; ks < 2; ++ks)
        a[fm][ks] = *(const short8*)(rdA + fm * 2048 + (ks ? koff1 : koff0));
#pragma unroll
    for (int fn = 0; fn < 2; ++fn)
#pragma unroll
      for (int ks = 0; ks < 2; ++ks)
        b0[fn][ks] = *(const short8*)(rdB + fn * 2048 + (ks ? koff1 : koff0));
    if (t + 1 < NT) stageA(db ^ 1, 0, t + 1);
    PH_BAR;
    __builtin_amdgcn_s_setprio(1);
#pragma unroll
    for (int fm = 0; fm < 4; ++fm)
#pragma unroll
      for (int fn = 0; fn < 2; ++fn)
#pragma unroll
        for (int ks = 0; ks < 2; ++ks)
          acc[fm][fn] = __builtin_amdgcn_mfma_f32_16x16x32_bf16(a[fm][ks], b0[fn][ks], acc[fm][fn], 0, 0, 0);
    __builtin_amdgcn_s_setprio(0);
    PH_BAR;

    // ---- phase 2: quadrant (m-lo, n-hi) ----
#pragma unroll
    for (int fn = 0; fn < 2; ++fn)
#pragma unroll
      for (int ks = 0; ks < 2; ++ks)
        b1[fn][ks] = *(const short8*)(rdB + (2 + fn) * 2048 + (ks ? koff1 : koff0));
    if (t + 1 < NT) stageA(db ^ 1, 1, t + 1);
    PH_BAR;
    __builtin_amdgcn_s_setprio(1);
#pragma unroll
    for (int fm = 0; fm < 4; ++fm)
#pragma unroll
      for (int fn = 0; fn < 2; ++fn)
#pragma unroll
        for (int ks = 0; ks < 2; ++ks)
          acc[fm][2 + fn] = __builtin_amdgcn_mfma_f32_16x16x32_bf16(a[fm][ks], b1[fn][ks], acc[fm][2 + fn], 0, 0, 0);
    __builtin_amdgcn_s_setprio(0);
    PH_BAR;

    // ---- phase 3: quadrant (m-hi, n-lo) ----
#pragma unroll
    for (int fm = 0; fm < 4; ++fm)
#pragma unroll
      for (int ks = 0; ks < 2; ++ks)
        a[fm][ks] = *(const short8*)(rdA + (4 + fm) * 2048 + (ks ? koff1 : koff0));
    if (t + 2 < NT) stageB(db, 0, t + 2);
    PH_BAR;
    __builtin_amdgcn_s_setprio(1);
#pragma unroll
    for (int fm = 0; fm < 4; ++fm)
#pragma unroll
      for (int fn = 0; fn < 2; ++fn)
#pragma unroll
        for (int ks = 0; ks < 2; ++ks)
          acc[4 + fm][fn] = __builtin_amdgcn_mfma_f32_16x16x32_bf16(a[fm][ks], b0[fn][ks], acc[4 + fm][fn], 0, 0, 0);
    __builtin_amdgcn_s_setprio(0);
    PH_BAR;

    // ---- phase 4: quadrant (m-hi, n-hi) ----
    if (t + 2 < NT) stageB(db, 1, t + 2);
    PH_BAR;
    __builtin_amdgcn_s_setprio(1);
#pragma unroll
    for (int fm = 0; fm < 4; ++fm)
#pragma unroll
      for (int fn = 0; fn < 2; ++fn)
#pragma unroll
        for (int ks = 0; ks < 2; ++ks)
          acc[4 + fm][2 + fn] = __builtin_amdgcn_mfma_f32_16x16x32_bf16(a[fm][ks], b1[fn][ks], acc[4 + fm][2 + fn], 0, 0, 0);
    __builtin_amdgcn_s_setprio(0);
    if (t + 2 < NT) { WAITV(4); }
    else if (t + 1 < NT) { WAITV(0); }
    PH_BAR;
  }

  // epilogue: C row = (lane>>4)*4 + r, col = lane&15 (verified layout)
  const int ci = (lane >> 4) * 4;
  if (MODE == 0) {
    const int seg = n0 >> 11;            // 0=q, 1=k, 2=v (tiles never straddle)
    u16* Cb = (seg == 0) ? Oq : ((seg == 1) ? Ok : Ov);
    const float scale = (seg == 0) ? (1.0f / 128.0f) : 1.0f;
    const int nl0 = n0 & (Dn - 1);
#pragma unroll
    for (int fm = 0; fm < 8; ++fm)
#pragma unroll
      for (int fn = 0; fn < 4; ++fn) {
        int row = m0 + wm * 128 + fm * 16 + ci;
        int col = nl0 + wn * 64 + fn * 16 + fr;
#pragma unroll
        for (int r = 0; r < 4; ++r)
          Cb[(size_t)(row + r) * Dn + col] = f2bf(acc[fm][fn][r] * scale);
      }
  } else {
#pragma unroll
    for (int fm = 0; fm < 8; ++fm)
#pragma unroll
      for (int fn = 0; fn < 4; ++fn) {
        int row = m0 + wm * 128 + fm * 16 + ci;
        int col = n0 + wn * 64 + fn * 16 + fr;
#pragma unroll
        for (int r = 0; r < 4; ++r)
          Of[(size_t)(row + r) * Dn + col] = acc[fm][fn][r];
      }
  }
}

// ---------------- v (B,T,D) -> vT (B,D,T) transpose ----------------
__global__ __launch_bounds__(256) void transpose_kernel(
    const u16* __restrict__ vin, u16* __restrict__ vout) {
  __shared__ u16 tile[64][72];   // +8 pad
  const int b = blockIdx.z;
  const int t0 = blockIdx.x * 64, d0 = blockIdx.y * 64;
  const int tid = threadIdx.x;
#pragma unroll
  for (int i = 0; i < 2; ++i) {
    int chunk = tid + i * 256;          // 512 chunks of 8 elems
    int row = chunk >> 3;               // t
    int col = (chunk & 7) * 8;          // d
    u16x8 v = *reinterpret_cast<const u16x8*>(
        vin + ((size_t)b * Tn + t0 + row) * Dn + d0 + col);
#pragma unroll
    for (int j = 0; j < 8; ++j) tile[row][col + j] = v[j];
  }
  __syncthreads();
#pragma unroll
  for (int i = 0; i < 2; ++i) {
    int chunk = tid + i * 256;
    int drow = chunk >> 3;              // d
    int tcol = (chunk & 7) * 8;         // t
    u16x8 v;
#pragma unroll
    for (int j = 0; j < 8; ++j) v[j] = tile[tcol + j][drow];
    *reinterpret_cast<u16x8*>(vout + ((size_t)b * Dn + d0 + drow) * Tn + t0 + tcol) = v;
  }
}

// ---------------- block attention ----------------
// 1 WG per (b, blk). 8 waves / 512 threads.
// phase1: sim (128x256) = Qblk @ K2^T, BK=64, swizzled 128B-row LDS tiles
// phase2: mask + relu^2 -> P bf16 in LDS [128][264]
// phase3: out = P @ V2, 32 chunks of 64 d-cols, Vts 512B rows swizzled
__global__ __launch_bounds__(512) void attn_kernel(
    const u16* __restrict__ q, const u16* __restrict__ k,
    const u16* __restrict__ vT, u16* __restrict__ ao) {
  __shared__ u16 sStage[24576];        // 48KB: ph1 Qs 16KB + Ks 32KB; ph3 Vts 32KB
  __shared__ u16 sP[128 * 264];        // 67.6KB
  u16* Qs = sStage;                    // 128 rows x 64 elems (128B rows)
  u16* Ks = sStage + 8192;             // 256 rows x 64
  u16* Vts = sStage;                   // 64 rows(d) x 256 elems(t) (512B rows)

  const int bid = blockIdx.x;
  const int b = bid >> 6, blk = bid & 63;
  const int tid = threadIdx.x, lane = tid & 63, wid = tid >> 6;
  const int tprev = blk * 128 - 128;

  const u16* qp = q + ((size_t)b * Tn + blk * 128) * Dn;
  const u16* kp = k + (size_t)b * Tn * Dn;
  const u16* vp = vT + (size_t)b * Dn * Tn;

  const int wm = wid >> 2, wn = wid & 3;     // 2x4 wave grid
  const int fr = lane & 15;
  const int kkb = (lane >> 4) * 16;

  // swizzle constants (same scheme as gemm256)
  const int frb2 = (fr >> 2) & 1;
  const int rdoff = fr * 128 + (kkb ^ ((fr & 3) << 4));
  const int koff0 = frb2 * 64;
  const int koff1 = 64 - koff0;
  const int srow8 = lane >> 3;
  const int scol8 = ((lane & 7) ^ srow8) * 8;

  // ---- phase 1: sim = Q @ K2^T, BK=64 ----
  f32x4 acc[4][4] = {};
  for (int k0 = 0; k0 < Dn; k0 += 64) {
#pragma unroll
    for (int i = 0; i < 2; ++i) {                // Q: 16 chunks of 8 rows
      int chunk = wid * 2 + i;
      int row = chunk * 8 + srow8;
      gload16((char*)Qs + chunk * 1024, qp + (size_t)row * Dn + k0 + scol8);
    }
#pragma unroll
    for (int i = 0; i < 4; ++i) {                // K: 32 chunks of 8 rows
      int chunk = wid * 4 + i;
      int trow = tprev + chunk * 8 + srow8;
      if (trow < 0) trow = 0;                    // pad rows: masked in phase 2
      gload16((char*)Ks + chunk * 1024, kp + (size_t)trow * Dn + k0 + scol8);
    }
    __syncthreads();
    short8 av[4][2], bv[4][2];
    const char* qbase = (const char*)Qs + wm * 8192 + rdoff;
    const char* kbase = (const char*)Ks + wn * 8192 + rdoff;
#pragma unroll
    for (int f = 0; f < 4; ++f)
#pragma unroll
      for (int ks = 0; ks < 2; ++ks) {
        av[f][ks] = *(const short8*)(qbase + f * 2048 + (ks ? koff1 : koff0));
        bv[f][ks] = *(const short8*)(kbase + f * 2048 + (ks ? koff1 : koff0));
      }
#pragma unroll
    for (int fm = 0; fm < 4; ++fm)
#pragma unroll
      for (int fn = 0; fn < 4; ++fn)
#pragma unroll
        for (int ks = 0; ks < 2; ++ks)
          acc[fm][fn] = __builtin_amdgcn_mfma_f32_16x16x32_bf16(av[fm][ks], bv[fn][ks], acc[fm][fn], 0, 0, 0);
    __syncthreads();
  }

  // ---- phase 2: mask + relu^2 -> P ----
  {
    const int ci = (lane >> 4) * 4;
#pragma unroll
    for (int fm = 0; fm < 4; ++fm)
#pragma unroll
      for (int fn = 0; fn < 4; ++fn)
#pragma unroll
        for (int r = 0; r < 4; ++r) {
          int i = wm * 64 + fm * 16 + ci + r;     // query row 0..127
          int j = wn * 64 + fn * 16 + fr;         // key 0..255 (0..127 = prev)
          float s = acc[fm][fn][r];
          bool keep = (j < 128) ? (blk > 0 && i <= j) : (i >= j - 128);
          float p = (keep && s > 0.0f) ? s * s : 0.0f;
          sP[i * 264 + j] = f2bf(p);
        }
  }
  __syncthreads();

  // ---- phase 3: out = P @ V2, Vts rows 512B, swizzled ----
  const int vrow_c = lane >> 5;                  // stage row within 2-row chunk
  for (int c = 0; c < 32; ++c) {
#pragma unroll
    for (int i = 0; i < 4; ++i) {
      int chunk = wid * 4 + i;
      int row = chunk * 2 + vrow_c;              // LDS d-row 0..63
      int d = c * 64 + row;
      int t = tprev + (((lane & 31) ^ (row & 7)) * 8);
      if (t < 0) t = 0;                          // pad: P is 0 there
      gload16((char*)Vts + chunk * 1024, vp + (size_t)d * Tn + t);
    }
    __syncthreads();
    f32x4 pacc[4] = {};
    const char* vb0 = (const char*)Vts + fr * 512 + (kkb ^ ((fr & 3) << 4)) + koff0;
    const char* vb1 = (const char*)Vts + fr * 512 + (kkb ^ ((fr & 3) << 4)) + koff1;
    const char* pbase = (const char*)sP + (wid * 16 + fr) * 528 + kkb;
#pragma unroll
    for (int ks = 0; ks < 8; ++ks) {
      short8 a = *(const short8*)(pbase + ks * 64);
#pragma unroll
      for (int fn = 0; fn < 4; ++fn) {
        const char* vb = ((ks & 1) ? vb1 : vb0) + fn * 8192 + (ks >> 1) * 128;
        short8 bv2 = *(const short8*)vb;
        pacc[fn] = __builtin_amdgcn_mfma_f32_16x16x32_bf16(a, bv2, pacc[fn], 0, 0, 0);
      }
    }
    const int ci = (lane >> 4) * 4;
    int trow = blk * 128 + wid * 16 + ci;
#pragma unroll
    for (int fn = 0; fn < 4; ++fn) {
      int d = c * 64 + fn * 16 + fr;
#pragma unroll
      for (int r = 0; r < 4; ++r)
        ao[((size_t)b * Tn + trow + r) * Dn + d] = f2bf(pacc[fn][r]);
    }
    __syncthreads();
  }
}

extern "C" void kernel_launch(void* const* d_in, const int* in_sizes, int n_in,
                              void* d_out, int out_size, void* d_ws, size_t ws_size,
                              hipStream_t stream) {
  const float* x = (const float*)d_in[0];
  const float* w_attn = (const float*)d_in[1];
  const float* w_o = (const float*)d_in[2];
  float* out = (float*)d_out;

  char* ws = (char*)d_ws;
  u16* xb  = (u16*)(ws + 0);            // 64 MB  (B*T*D)
  u16* wb  = (u16*)(ws + 67108864);     // 24 MB  (3D*D)
  u16* wob = (u16*)(ws + 92274688);     // 8 MB   (D*D)
  u16* qb  = (u16*)(ws + 100663296);    // 64 MB
  u16* kb  = (u16*)(ws + 167772160);    // 64 MB
  u16* vb  = (u16*)(ws + 234881024);    // 64 MB
  u16* vTb = xb;   // reuse: xb dead after QKV GEMM
  u16* ao  = vb;   // reuse: vb dead after transpose

  cast_kernel<<<2048, 256, 0, stream>>>(x, xb, Bn * Tn * Dn);
  cast_kernel<<<1024, 256, 0, stream>>>(w_attn, wb, 3 * Dn * Dn);
  cast_kernel<<<512, 256, 0, stream>>>(w_o, wob, Dn * Dn);

  // qkv = x @ w_attn^T  (M=16384, N=6144, K=2048)
  gemm256<0><<<dim3(64, 24), 512, 0, stream>>>(xb, wb, qb, kb, vb, nullptr, Dn);

  // vT (B,D,T)
  transpose_kernel<<<dim3(128, 32, 2), 256, 0, stream>>>(vb, vTb);

  // block attention
  attn_kernel<<<128, 512, 0, stream>>>(qb, kb, vTb, ao);

  // out = attn_out @ w_o^T  (M=16384, N=2048, K=2048), fp32 out
  gemm256<1><<<dim3(64, 8), 512, 0, stream>>>(ao, wob, nullptr, nullptr, nullptr, out, Dn);
}